// Round 2
// baseline (293.070 us; speedup 1.0000x reference)
//
#include <hip/hip_runtime.h>

#define RAYS 65536
#define NS   192

__device__ __forceinline__ int   f2i(float x){ return __builtin_bit_cast(int, x); }
__device__ __forceinline__ float i2f(int x)  { return __builtin_bit_cast(float, x); }

// v_mov_b32_dpp with old=0, bound_ctrl:0 (invalid lanes -> 0)
template<int CTRL, int ROWMASK>
__device__ __forceinline__ float dpp0(float x){
    return i2f(__builtin_amdgcn_update_dpp(0, f2i(x), CTRL, ROWMASK, 0xF, true));
}
template<int OFF>
__device__ __forceinline__ float swz(float x){
    return i2f(__builtin_amdgcn_ds_swizzle(f2i(x), OFF));
}

// partner value at sub-lane XOR distance JL (within each 32-lane half)
template<int JL>
__device__ __forceinline__ float partner(float x){
    if      constexpr (JL == 1)  return dpp0<0xB1, 0xF>(x);   // quad_perm xor1
    else if constexpr (JL == 2)  return dpp0<0x4E, 0xF>(x);   // quad_perm xor2
    else if constexpr (JL == 3)  return dpp0<0x1B, 0xF>(x);   // quad_perm [3,2,1,0] = xor3
    else if constexpr (JL == 4)  return swz<0x101F>(x);       // xor4
    else if constexpr (JL == 7)  return swz<0x1C1F>(x);       // xor7
    else if constexpr (JL == 8)  return swz<0x201F>(x);       // xor8
    else if constexpr (JL == 15) return swz<0x3C1F>(x);       // xor15
    else if constexpr (JL == 16) return swz<0x401F>(x);       // xor16
    else                         return swz<0x7C1F>(x);       // xor31
}

// ascending in-lane compare-exchange: 2 VALU (fmin+fmax)
__device__ __forceinline__ void ce(float &a, float &b){
    float mn = fminf(a, b), mx = fmaxf(a, b);
    a = mn; b = mx;
}

// normalized cross-lane halver phase at lane distance JL; 'lower' = ((sl&JL)==0).
// keep own value iff (v < p) == lower.
template<int JL>
__device__ __forceinline__ void xphase(float v[8], bool lower){
    #pragma unroll
    for (int r = 0; r < 8; ++r){
        float p = partner<JL>(v[r]);
        v[r] = ((v[r] < p) == lower) ? v[r] : p;
    }
}

// mirror phase opening a merge of two ascending runs: element (sl, r) pairs
// with (sl^JL, 7-r). 'lower' = this lane is in the lower half of the block.
// pairs (r, 7-r) are disjoint, so in-place pairwise update is safe.
template<int JL>
__device__ __forceinline__ void xmirror(float v[8], bool lower){
    #pragma unroll
    for (int r = 0; r < 4; ++r){
        float pa = partner<JL>(v[7 - r]);   // partner's mirrored element for v[r]
        float pb = partner<JL>(v[r]);       // partner's mirrored element for v[7-r]
        v[r]     = ((v[r]     < pa) == lower) ? v[r]     : pa;
        v[7 - r] = ((v[7 - r] < pb) == lower) ? v[7 - r] : pb;
    }
}

// in-lane bitonic cleanup (strides 4,2,1), ascending
__device__ __forceinline__ void rmerge(float v[8]){
    ce(v[0],v[4]); ce(v[1],v[5]); ce(v[2],v[6]); ce(v[3],v[7]);
    ce(v[0],v[2]); ce(v[1],v[3]); ce(v[4],v[6]); ce(v[5],v[7]);
    ce(v[0],v[1]); ce(v[2],v[3]); ce(v[4],v[5]); ce(v[6],v[7]);
}

// Batcher odd-even 8-sorter, 19 CEs, ascending
__device__ __forceinline__ void sort8(float v[8]){
    ce(v[0],v[1]); ce(v[2],v[3]); ce(v[4],v[5]); ce(v[6],v[7]);
    ce(v[0],v[2]); ce(v[1],v[3]); ce(v[4],v[6]); ce(v[5],v[7]);
    ce(v[1],v[2]); ce(v[5],v[6]);
    ce(v[0],v[4]); ce(v[1],v[5]); ce(v[2],v[6]); ce(v[3],v[7]);
    ce(v[2],v[4]); ce(v[3],v[5]);
    ce(v[1],v[2]); ce(v[3],v[4]); ce(v[5],v[6]);
}

// 32-lane butterfly sum (both halves independently)
__device__ __forceinline__ float halfsum(float a){
    a += dpp0<0xB1, 0xF>(a);
    a += dpp0<0x4E, 0xF>(a);
    a += swz<0x101F>(a);
    a += swz<0x201F>(a);
    a += swz<0x401F>(a);
    return a;
}

__global__ __launch_bounds__(256) void nerf_integrate(
    const float* __restrict__ t,
    const float* __restrict__ sigma,
    const float* __restrict__ c,
    float* __restrict__ out)
{
    const int tid  = threadIdx.x;
    const int lane = tid & 63;
    const int sl   = tid & 31;                     // sub-lane within the ray's 32 lanes
    const int ray  = blockIdx.x * 8 + (tid >> 5);  // 2 rays per wave, 8 per block

    const bool lo1  = (sl & 1)  == 0;
    const bool lo2  = (sl & 2)  == 0;
    const bool lo4  = (sl & 4)  == 0;
    const bool lo8  = (sl & 8)  == 0;
    const bool lo16 = (sl & 16) == 0;

    // ---- coalesced t load: placement is irrelevant pre-sort ----
    // v[j] = t[32*j + sl]  (6 fully-coalesced dword rounds), tail in lane 0
    const float* trow = t + (size_t)ray * 193;
    float v[8];
    #pragma unroll
    for (int j = 0; j < 6; ++j) v[j] = trow[32 * j + sl];
    v[6] = (sl == 0) ? trow[192] : 1e30f;
    v[7] = 1e30f;

    // ---- PREFETCH sigma & c before the sort: their addresses don't depend
    //      on the sort, and the ~1500-cycle sort chain hides the HBM latency.
    const bool act = (sl < 24);                    // lane's 8 elements all < 192
    float sg[8];
    float cf[24];
    if (act){
        const float* srow = sigma + (size_t)ray * NS + 8 * sl;
        float4 s0 = *reinterpret_cast<const float4*>(srow);
        float4 s1 = *reinterpret_cast<const float4*>(srow + 4);
        sg[0]=s0.x; sg[1]=s0.y; sg[2]=s0.z; sg[3]=s0.w;
        sg[4]=s1.x; sg[5]=s1.y; sg[6]=s1.z; sg[7]=s1.w;
        const float* crow = c + (size_t)ray * (NS * 3) + 24 * sl;
        #pragma unroll
        for (int m = 0; m < 6; ++m){
            float4 cc = *reinterpret_cast<const float4*>(crow + 4 * m);
            cf[4*m+0]=cc.x; cf[4*m+1]=cc.y; cf[4*m+2]=cc.z; cf[4*m+3]=cc.w;
        }
    } else {
        #pragma unroll
        for (int r = 0; r < 8; ++r) sg[r] = 0.0f;
    }

    // ==== mirror-normalized bitonic sort of 256: bits [2:0]=r, [7:3]=sl ====
    // every run ascending; each merge = mirror phase + xor halvers. no sign flips.
    sort8(v);
    // merge to 16
    xmirror<1>(v, lo1);
    rmerge(v);
    // merge to 32
    xmirror<3>(v, lo2);
    xphase<1>(v, lo1);
    rmerge(v);
    // merge to 64
    xmirror<7>(v, lo4);
    xphase<2>(v, lo2);
    xphase<1>(v, lo1);
    rmerge(v);
    // merge to 128
    xmirror<15>(v, lo8);
    xphase<4>(v, lo4);
    xphase<2>(v, lo2);
    xphase<1>(v, lo1);
    rmerge(v);
    // merge to 256
    xmirror<31>(v, lo16);
    xphase<8>(v, lo8);
    xphase<4>(v, lo4);
    xphase<2>(v, lo2);
    xphase<1>(v, lo1);
    rmerge(v);

    // ---- neighbor for r=7 (cross-lane before any divergence) ----
    float nxt = __shfl(v[0], lane + 1, 64);  // lane31/63 are pads -> don't care

    // ---- sdt ----
    float sdt[8];
    #pragma unroll
    for (int r = 0; r < 8; ++r){
        float tn = (r < 7) ? v[r + 1] : nxt;
        sdt[r] = act ? sg[r] * (tn - v[r]) : 0.0f;
    }

    // ---- prefix sum: in-lane inclusive over 8, then per-half DPP scan ----
    float pre[8];
    float run = 0.0f;
    #pragma unroll
    for (int r = 0; r < 8; ++r){ run += sdt[r]; pre[r] = run; }
    float x = run;
    x += dpp0<0x111, 0xF>(x);   // row_shr:1
    x += dpp0<0x112, 0xF>(x);   // row_shr:2
    x += dpp0<0x114, 0xF>(x);   // row_shr:4
    x += dpp0<0x118, 0xF>(x);   // row_shr:8
    x += dpp0<0x142, 0xA>(x);   // row_bcast:15 into rows 1,3 (per-half scan)
    float laneExcl = x - run;

    // ---- wi via telescoped exponentials: excl_r == incl_{r-1} -> 9 exps ----
    float wi[8];
    float prev = __expf(-laneExcl);
    #pragma unroll
    for (int r = 0; r < 8; ++r){
        float e = __expf(-(laneExcl + pre[r]));
        wi[r] = prev - e;
        prev = e;
    }
    if (act){
        float* wrow = out + (size_t)RAYS * 3 + (size_t)ray * NS + 8 * sl;
        *reinterpret_cast<float4*>(wrow)     = make_float4(wi[0], wi[1], wi[2], wi[3]);
        *reinterpret_cast<float4*>(wrow + 4) = make_float4(wi[4], wi[5], wi[6], wi[7]);
    }

    // ---- rgb from prefetched cf, per-half reduce ----
    float a0 = 0.f, a1 = 0.f, a2 = 0.f;
    if (act){
        #pragma unroll
        for (int r = 0; r < 8; ++r){
            a0 += wi[r] * cf[3*r + 0];
            a1 += wi[r] * cf[3*r + 1];
            a2 += wi[r] * cf[3*r + 2];
        }
    }
    a0 = halfsum(a0);
    a1 = halfsum(a1);
    a2 = halfsum(a2);
    if (sl < 3){
        float val = (sl == 0) ? a0 : ((sl == 1) ? a1 : a2);
        out[(size_t)ray * 3 + sl] = val;
    }
}

extern "C" void kernel_launch(void* const* d_in, const int* in_sizes, int n_in,
                              void* d_out, int out_size, void* d_ws, size_t ws_size,
                              hipStream_t stream) {
    const float* t     = (const float*)d_in[0];
    const float* sigma = (const float*)d_in[1];
    const float* c     = (const float*)d_in[2];
    float* out = (float*)d_out;
    nerf_integrate<<<RAYS / 8, 256, 0, stream>>>(t, sigma, c, out);
}

// Round 3
// 292.509 us; speedup vs baseline: 1.0019x; 1.0019x over previous
//
#include <hip/hip_runtime.h>

#define RAYS 65536
#define NS   192

__device__ __forceinline__ int   f2i(float x){ return __builtin_bit_cast(int, x); }
__device__ __forceinline__ float i2f(int x)  { return __builtin_bit_cast(float, x); }

// v_mov_b32_dpp with old=0, bound_ctrl:0 (invalid lanes -> 0)
template<int CTRL, int ROWMASK>
__device__ __forceinline__ float dpp0(float x){
    return i2f(__builtin_amdgcn_update_dpp(0, f2i(x), CTRL, ROWMASK, 0xF, true));
}
template<int OFF>
__device__ __forceinline__ float swz(float x){
    return i2f(__builtin_amdgcn_ds_swizzle(f2i(x), OFF));
}

// partner value at sub-lane XOR distance JL (within each 32-lane half)
template<int JL>
__device__ __forceinline__ float partner(float x){
    if      constexpr (JL == 1)  return dpp0<0xB1, 0xF>(x);   // quad_perm xor1
    else if constexpr (JL == 2)  return dpp0<0x4E, 0xF>(x);   // quad_perm xor2
    else if constexpr (JL == 3)  return dpp0<0x1B, 0xF>(x);   // quad_perm [3,2,1,0] = xor3
    else if constexpr (JL == 4)  return swz<0x101F>(x);       // xor4
    else if constexpr (JL == 7)  return swz<0x1C1F>(x);       // xor7
    else if constexpr (JL == 8)  return swz<0x201F>(x);       // xor8
    else if constexpr (JL == 15) return swz<0x3C1F>(x);       // xor15
    else if constexpr (JL == 16) return swz<0x401F>(x);       // xor16
    else                         return swz<0x7C1F>(x);       // xor31
}

// ascending in-lane compare-exchange: 2 VALU (fmin+fmax)
__device__ __forceinline__ void ce(float &a, float &b){
    float mn = fminf(a, b), mx = fmaxf(a, b);
    a = mn; b = mx;
}

// normalized cross-lane halver phase at lane distance JL; 'lower' = ((sl&JL)==0).
template<int JL>
__device__ __forceinline__ void xphase(float v[8], bool lower){
    #pragma unroll
    for (int r = 0; r < 8; ++r){
        float p = partner<JL>(v[r]);
        v[r] = ((v[r] < p) == lower) ? v[r] : p;
    }
}

// mirror phase opening a merge of two ascending runs: (sl, r) pairs with (sl^JL, 7-r).
template<int JL>
__device__ __forceinline__ void xmirror(float v[8], bool lower){
    #pragma unroll
    for (int r = 0; r < 4; ++r){
        float pa = partner<JL>(v[7 - r]);
        float pb = partner<JL>(v[r]);
        v[r]     = ((v[r]     < pa) == lower) ? v[r]     : pa;
        v[7 - r] = ((v[7 - r] < pb) == lower) ? v[7 - r] : pb;
    }
}

// in-lane bitonic cleanup (strides 4,2,1), ascending
__device__ __forceinline__ void rmerge(float v[8]){
    ce(v[0],v[4]); ce(v[1],v[5]); ce(v[2],v[6]); ce(v[3],v[7]);
    ce(v[0],v[2]); ce(v[1],v[3]); ce(v[4],v[6]); ce(v[5],v[7]);
    ce(v[0],v[1]); ce(v[2],v[3]); ce(v[4],v[5]); ce(v[6],v[7]);
}

// Batcher odd-even 8-sorter, 19 CEs, ascending
__device__ __forceinline__ void sort8(float v[8]){
    ce(v[0],v[1]); ce(v[2],v[3]); ce(v[4],v[5]); ce(v[6],v[7]);
    ce(v[0],v[2]); ce(v[1],v[3]); ce(v[4],v[6]); ce(v[5],v[7]);
    ce(v[1],v[2]); ce(v[5],v[6]);
    ce(v[0],v[4]); ce(v[1],v[5]); ce(v[2],v[6]); ce(v[3],v[7]);
    ce(v[2],v[4]); ce(v[3],v[5]);
    ce(v[1],v[2]); ce(v[3],v[4]); ce(v[5],v[6]);
}

// 32-lane butterfly sum (both halves independently)
__device__ __forceinline__ float halfsum(float a){
    a += dpp0<0xB1, 0xF>(a);
    a += dpp0<0x4E, 0xF>(a);
    a += swz<0x101F>(a);
    a += swz<0x201F>(a);
    a += swz<0x401F>(a);
    return a;
}

__global__ __launch_bounds__(256) void nerf_integrate(
    const float* __restrict__ t,
    const float* __restrict__ sigma,
    const float* __restrict__ c,
    float* __restrict__ out)
{
    const int tid  = threadIdx.x;
    const int lane = tid & 63;
    const int sl   = tid & 31;                     // sub-lane within the ray's 32 lanes
    const int ray  = blockIdx.x * 8 + (tid >> 5);  // 2 rays per wave, 8 per block

    const bool lo1  = (sl & 1)  == 0;
    const bool lo2  = (sl & 2)  == 0;
    const bool lo4  = (sl & 4)  == 0;
    const bool lo8  = (sl & 8)  == 0;
    const bool lo16 = (sl & 16) == 0;

    const bool act = (sl < 24);                    // lane's 8 elements all < 192
    const int  sls = act ? sl : 0;                 // clamped: inactive lanes load row
                                                   // start (finite garbage, never used)

    // ======== ISSUE ALL LOADS UP FRONT (latency hidden under the sort) ========
    // t: coalesced, placement irrelevant pre-sort: v[j] = t[32*j + sl]
    const float* trow = t + (size_t)ray * 193;
    float v[8];
    #pragma unroll
    for (int j = 0; j < 6; ++j) v[j] = trow[32 * j + sl];
    float t192 = trow[192];                        // same addr all lanes (1 line)

    const float* srow = sigma + (size_t)ray * NS + 8 * sls;
    float4 s0 = *reinterpret_cast<const float4*>(srow);
    float4 s1 = *reinterpret_cast<const float4*>(srow + 4);

    const float* crow = c + (size_t)ray * (NS * 3) + 24 * sls;
    float4 c0 = *reinterpret_cast<const float4*>(crow);
    float4 c1 = *reinterpret_cast<const float4*>(crow + 4);
    float4 c2 = *reinterpret_cast<const float4*>(crow + 8);
    float4 c3 = *reinterpret_cast<const float4*>(crow + 12);
    float4 c4 = *reinterpret_cast<const float4*>(crow + 16);
    float4 c5 = *reinterpret_cast<const float4*>(crow + 20);

    // pin the loads above the sort: nothing may be scheduled across this
    __builtin_amdgcn_sched_barrier(0);

    v[6] = (sl == 0) ? t192 : 1e30f;
    v[7] = 1e30f;

    // ==== mirror-normalized bitonic sort of 256: bits [2:0]=r, [7:3]=sl ====
    sort8(v);
    // merge to 16
    xmirror<1>(v, lo1);
    rmerge(v);
    // merge to 32
    xmirror<3>(v, lo2);
    xphase<1>(v, lo1);
    rmerge(v);
    // merge to 64
    xmirror<7>(v, lo4);
    xphase<2>(v, lo2);
    xphase<1>(v, lo1);
    rmerge(v);
    // merge to 128
    xmirror<15>(v, lo8);
    xphase<4>(v, lo4);
    xphase<2>(v, lo2);
    xphase<1>(v, lo1);
    rmerge(v);
    // merge to 256
    xmirror<31>(v, lo16);
    xphase<8>(v, lo8);
    xphase<4>(v, lo4);
    xphase<2>(v, lo2);
    xphase<1>(v, lo1);
    rmerge(v);

    // ---- neighbor for r=7 (cross-lane, uniform control flow) ----
    float nxt = __shfl(v[0], lane + 1, 64);  // lane31/63 are pads -> don't care

    // ---- sdt (act-select zeroes inactive lanes; garbage sg never escapes) ----
    float sg[8] = { s0.x, s0.y, s0.z, s0.w, s1.x, s1.y, s1.z, s1.w };
    float sdt[8];
    #pragma unroll
    for (int r = 0; r < 8; ++r){
        float tn = (r < 7) ? v[r + 1] : nxt;
        sdt[r] = act ? sg[r] * (tn - v[r]) : 0.0f;
    }

    // ---- prefix sum: in-lane inclusive over 8, then per-half DPP scan ----
    float pre[8];
    float run = 0.0f;
    #pragma unroll
    for (int r = 0; r < 8; ++r){ run += sdt[r]; pre[r] = run; }
    float x = run;
    x += dpp0<0x111, 0xF>(x);   // row_shr:1
    x += dpp0<0x112, 0xF>(x);   // row_shr:2
    x += dpp0<0x114, 0xF>(x);   // row_shr:4
    x += dpp0<0x118, 0xF>(x);   // row_shr:8
    x += dpp0<0x142, 0xA>(x);   // row_bcast:15 into rows 1,3 (per-half scan)
    float laneExcl = x - run;

    // ---- wi via telescoped exponentials: excl_r == incl_{r-1} -> 9 exps ----
    // inactive lanes: all sdt==0 -> wi==0 exactly, so 0*garbage below is safe.
    float wi[8];
    float prev = __expf(-laneExcl);
    #pragma unroll
    for (int r = 0; r < 8; ++r){
        float e = __expf(-(laneExcl + pre[r]));
        wi[r] = prev - e;
        prev = e;
    }
    if (act){
        float* wrow = out + (size_t)RAYS * 3 + (size_t)ray * NS + 8 * sl;
        *reinterpret_cast<float4*>(wrow)     = make_float4(wi[0], wi[1], wi[2], wi[3]);
        *reinterpret_cast<float4*>(wrow + 4) = make_float4(wi[4], wi[5], wi[6], wi[7]);
    }

    // ---- rgb from prefetched c, per-half reduce (wi==0 kills garbage lanes) ----
    float cf[24] = { c0.x,c0.y,c0.z,c0.w, c1.x,c1.y,c1.z,c1.w,
                     c2.x,c2.y,c2.z,c2.w, c3.x,c3.y,c3.z,c3.w,
                     c4.x,c4.y,c4.z,c4.w, c5.x,c5.y,c5.z,c5.w };
    float a0 = 0.f, a1 = 0.f, a2 = 0.f;
    #pragma unroll
    for (int r = 0; r < 8; ++r){
        a0 += wi[r] * cf[3*r + 0];
        a1 += wi[r] * cf[3*r + 1];
        a2 += wi[r] * cf[3*r + 2];
    }
    a0 = halfsum(a0);
    a1 = halfsum(a1);
    a2 = halfsum(a2);
    if (sl < 3){
        float val = (sl == 0) ? a0 : ((sl == 1) ? a1 : a2);
        out[(size_t)ray * 3 + sl] = val;
    }
}

extern "C" void kernel_launch(void* const* d_in, const int* in_sizes, int n_in,
                              void* d_out, int out_size, void* d_ws, size_t ws_size,
                              hipStream_t stream) {
    const float* t     = (const float*)d_in[0];
    const float* sigma = (const float*)d_in[1];
    const float* c     = (const float*)d_in[2];
    float* out = (float*)d_out;
    nerf_integrate<<<RAYS / 8, 256, 0, stream>>>(t, sigma, c, out);
}